// Round 12
// baseline (405.747 us; speedup 1.0000x reference)
//
#include <hip/hip_runtime.h>
#include <hip/hip_bf16.h>

typedef __attribute__((ext_vector_type(8))) short bf16x8;
typedef __attribute__((ext_vector_type(4))) float f32x4;

constexpr int Bc = 4, Sc = 2048, Dc = 512, Hc = 4;
constexpr float SCALE = 0.044194173824159216f; // 1/sqrt(512)

__device__ __forceinline__ unsigned short f2bf(float f) {
  union { float f; unsigned u; } v; v.f = f;
  unsigned r = v.u + 0x7fffu + ((v.u >> 16) & 1u);
  return (unsigned short)(r >> 16);
}

#define GLD16(GP, LP) __builtin_amdgcn_global_load_lds( \
    (const __attribute__((address_space(1))) unsigned int*)(GP), \
    (__attribute__((address_space(3))) unsigned int*)(LP), 16, 0, 0)

// ---------------- f32 -> bf16 convert (+scale) ----------------
__global__ __launch_bounds__(256) void k_cvt(const float* __restrict__ x,
                                             unsigned short* __restrict__ y, int n4,
                                             float scale) {
  int i = blockIdx.x * 256 + threadIdx.x;
  if (i < n4) {
    float4 v = ((const float4*)x)[i];
    ushort4 o;
    o.x = f2bf(v.x * scale); o.y = f2bf(v.y * scale);
    o.z = f2bf(v.z * scale); o.w = f2bf(v.w * scale);
    ((ushort4*)y)[i] = o;
  }
}

// ---------------- zero-fill f32 ----------------
__global__ __launch_bounds__(256) void k_zero(float* __restrict__ p, int n4) {
  int i = blockIdx.x * 256 + threadIdx.x;
  if (i < n4) ((float4*)p)[i] = float4{0.f, 0.f, 0.f, 0.f};
}

// ---------------- f32 -> bf16 copy (att finalize) ----------------
__global__ __launch_bounds__(256) void k_fin(const float* __restrict__ x,
                                             unsigned short* __restrict__ y, int n4) {
  int i = blockIdx.x * 256 + threadIdx.x;
  if (i < n4) {
    float4 v = ((const float4*)x)[i];
    ushort4 o;
    o.x = f2bf(v.x); o.y = f2bf(v.y); o.z = f2bf(v.z); o.w = f2bf(v.w);
    ((ushort4*)y)[i] = o;
  }
}

// ---------------- weight transpose + convert ----------------
__global__ __launch_bounds__(256) void k_wt(const float* __restrict__ W,
                                            unsigned short* __restrict__ WT,
                                            int K_, int N_, float scale) {
  const int z = blockIdx.z;
  W  += (size_t)z * K_ * N_;
  WT += (size_t)z * K_ * N_;
  __shared__ float t[32][33];
  const int k0 = blockIdx.x * 32, n0 = blockIdx.y * 32;
  const int tx = threadIdx.x & 31, ty = threadIdx.x >> 5;
#pragma unroll
  for (int i = 0; i < 32; i += 8) t[ty + i][tx] = W[(size_t)(k0 + ty + i) * N_ + n0 + tx];
  __syncthreads();
#pragma unroll
  for (int i = 0; i < 32; i += 8)
    WT[(size_t)(n0 + ty + i) * K_ + k0 + tx] = f2bf(t[tx][ty + i] * scale);
}

// ---------------- c[h,d'] = SCALE * sum_e bq[h,e] * Wk[h,d',e] ----------------
__global__ __launch_bounds__(256) void k_vecmat(const float* __restrict__ bqv,
                                                const float* __restrict__ Wk,
                                                float* __restrict__ cvec) {
  const int g = blockIdx.x * 256 + threadIdx.x;  // 2048 = 4h x 512d'
  const int h = g >> 9, d = g & 511;
  const float* wr = Wk + ((size_t)h * 512 + d) * 512;
  const float* bb = bqv + h * 512;
  float s = 0.f;
  for (int e = 0; e < 512; e += 4) {
    const float4 w = *(const float4*)(wr + e);
    const float4 q = *(const float4*)(bb + e);
    s += w.x * q.x + w.y * q.y + w.z * q.z + w.w * q.w;
  }
  cvec[g] = s * SCALE;
}

enum { EPI_MT = 0, EPI_QK = 1, EPI_V = 2, EPI_EXP = 3, EPI_PV = 4, EPI_RELU = 5, EPI_OUT = 6 };

// ---------------- proven 128^2 2-phase GEMM (R8/R11) ----------------
template <int EPI>
__global__ __launch_bounds__(256)
void k_gemm(const unsigned short* __restrict__ A, size_t sA,
            const unsigned short* __restrict__ BTg, size_t sB, int bzsh,
            const float* __restrict__ bias,
            void* __restrict__ outv, float* __restrict__ extra, int K)
{
  const int tid = threadIdx.x;
  const int w = tid >> 6, l = tid & 63;
  const int l15 = l & 15, lg = l >> 4;
  const int mb = blockIdx.x * 128, nb = blockIdx.y * 128;
  const int z = blockIdx.z;
  const int h = z;
  const unsigned short* Ae = A + (size_t)z * sA;
  const unsigned short* Be = BTg + (size_t)(z >> bzsh) * sB;

  __shared__ __align__(16) unsigned short As0[128 * 64], As1[128 * 64];
  __shared__ __align__(16) unsigned short Bs0[128 * 64], Bs1[128 * 64];

  f32x4 acc[4][4] = {};
  const int wm = w >> 1, wn = w & 1;
  const int mw = wm * 64, nw = wn * 64;
  const int nkt = K >> 6;

  auto stage = [&](int kb, unsigned short* Ad, unsigned short* Bd) {
#pragma unroll
    for (int i = 0; i < 4; ++i) {
      const int chunk = (w * 4 + i) * 64 + l;
      const int row = chunk >> 3;
      const int sb = ((chunk & 7) * 16) ^ ((row & 7) << 4);
      GLD16(Ae + (size_t)(mb + row) * K + kb + (sb >> 1), (char*)Ad + (w * 4 + i) * 1024);
      GLD16(Be + (size_t)(nb + row) * K + kb + (sb >> 1), (char*)Bd + (w * 4 + i) * 1024);
    }
  };
  auto compute = [&](const unsigned short* Asb, const unsigned short* Bsb) {
#pragma unroll
    for (int ks = 0; ks < 2; ++ks) {
      bf16x8 af[4], bfr[4];
#pragma unroll
      for (int m = 0; m < 4; ++m) {
        const int row = mw + m * 16 + l15;
        const int off = (ks * 64 + lg * 16) ^ ((row & 7) << 4);
        af[m] = *(const bf16x8*)((const char*)Asb + row * 128 + off);
      }
#pragma unroll
      for (int n = 0; n < 4; ++n) {
        const int row = nw + n * 16 + l15;
        const int off = (ks * 64 + lg * 16) ^ ((row & 7) << 4);
        bfr[n] = *(const bf16x8*)((const char*)Bsb + row * 128 + off);
      }
#pragma unroll
      for (int m = 0; m < 4; ++m)
#pragma unroll
        for (int n = 0; n < 4; ++n)
          acc[m][n] = __builtin_amdgcn_mfma_f32_16x16x32_bf16(af[m], bfr[n], acc[m][n], 0, 0, 0);
    }
  };

  stage(0, As0, Bs0);
  __syncthreads();
  for (int kt = 0; kt < nkt; kt += 2) {
    if (kt + 1 < nkt) stage((kt + 1) << 6, As1, Bs1);
    compute(As0, Bs0);
    __syncthreads();
    if (kt + 2 < nkt) stage((kt + 2) << 6, As0, Bs0);
    compute(As1, Bs1);
    __syncthreads();
  }

  if constexpr (EPI == EPI_MT) {
    unsigned short* op = (unsigned short*)outv;
#pragma unroll
    for (int m = 0; m < 4; ++m)
#pragma unroll
      for (int n = 0; n < 4; ++n) {
        const int col = nb + nw + n * 16 + l15;
#pragma unroll
        for (int r = 0; r < 4; ++r) {
          const int row = mb + mw + m * 16 + lg * 4 + r;
          op[((size_t)z * 512 + row) * 512 + col] = f2bf(acc[m][n][r]);
        }
      }
  } else if constexpr (EPI == EPI_QK || EPI == EPI_V) {
    unsigned short* op = (unsigned short*)outv;
#pragma unroll
    for (int m = 0; m < 4; ++m) {
#pragma unroll
      for (int n = 0; n < 4; ++n) {
        const int col = nb + nw + n * 16 + l15;
        const float bv = bias[h * Dc + col];
#pragma unroll
        for (int r = 0; r < 4; ++r) {
          const int row = mb + mw + m * 16 + lg * 4 + r;
          const float v = acc[m][n][r] + bv;
          const int bb = row >> 11, s = row & 2047;
          if constexpr (EPI == EPI_QK)
            op[(((size_t)bb * Hc + h) * Sc + s) * Dc + col] = f2bf(v);
          else
            op[(((size_t)bb * Hc + h) * Dc + col) * Sc + s] = f2bf(v);
        }
      }
    }
  } else if constexpr (EPI == EPI_PV) {
    float* of = (float*)outv + (size_t)(h >> 2) * 1048576;  // pair-local batch
#pragma unroll
    for (int m = 0; m < 4; ++m) {
#pragma unroll
      for (int r = 0; r < 4; ++r) {
        const int row = mb + mw + m * 16 + lg * 4 + r;
        const float il = 0.25f / extra[h * Sc + row];
#pragma unroll
        for (int n = 0; n < 4; ++n) {
          const int col = nb + nw + n * 16 + l15;
          atomicAdd(&of[(size_t)row * Dc + col], acc[m][n][r] * il);
        }
      }
    }
  } else {  // EPI_OUT
    float* of = (float*)outv;
#pragma unroll
    for (int m = 0; m < 4; ++m) {
#pragma unroll
      for (int n = 0; n < 4; ++n) {
        const int col = nb + nw + n * 16 + l15;
        const float bv = bias[col];
#pragma unroll
        for (int r = 0; r < 4; ++r) {
          const int row = mb + mw + m * 16 + lg * 4 + r;
          of[(size_t)row * Dc + col] = acc[m][n][r] + bv + extra[(size_t)row * Dc + col];
        }
      }
    }
  }
}

// ---------------- 256^2 8-wave counted-vmcnt phase-split GEMM (T3+T4+T5) ----------------
// 512 thr = 8 waves (2M x 4N), BM=BN=256, BK=64, per-wave C 128x64 (acc[8][4]).
// LDS 128 KiB: A/B double-buffered 256x64 tiles, proven ((row&7)<<4) swizzle.
// Per K-tile: stage A(t+1); vmcnt(4) [tile-t's 8 oldest done, A(t+1) stays in
// flight]; barrier; then 4 phases {ds_read A-frags; stage B(t+1) halves at
// q0/q1; barrier; lgkmcnt(0); setprio(1); 16 MFMA; setprio(0); barrier}.
// vmcnt never drains to 0 in the loop. All junctions sched_barrier(0)-fenced.
template <int EPI>
__global__ __launch_bounds__(512, 2)
void k_g8(const unsigned short* __restrict__ A, size_t sA,
          const unsigned short* __restrict__ BTg, size_t sB, int bzsh,
          const float* __restrict__ bias,
          void* __restrict__ outv, float* __restrict__ extra, int K)
{
  const int tid = threadIdx.x;
  const int w = tid >> 6, l = tid & 63;
  const int l15 = l & 15, lg = l >> 4;
  const int wm = w >> 2, wn = w & 3;
  const int mb = blockIdx.x * 256, nb = blockIdx.y * 256;
  const int z = blockIdx.z, h = z;
  const unsigned short* Abase = A + (size_t)z * sA + (size_t)mb * K;
  const unsigned short* Bbase = BTg + (size_t)(z >> bzsh) * sB + (size_t)nb * K;

  __shared__ __align__(16) unsigned short As0[256 * 64], As1[256 * 64];
  __shared__ __align__(16) unsigned short Bs0[256 * 64], Bs1[256 * 64];

  f32x4 acc[8][4] = {};
  const int nkt = K >> 6;

  // 2 sweeps (=2 GLD16/thread, 16 KB) of one matrix tile half into LDS.
  auto stg = [&](const unsigned short* gbase, int kb, unsigned short* dst, int half) {
#pragma unroll
    for (int s2 = 0; s2 < 2; ++s2) {
      const int s = half * 2 + s2;
      const int c = s * 512 + w * 64 + l;
      const int row = c >> 3;
      const int sb = ((c & 7) * 16) ^ ((row & 7) << 4);
      GLD16(gbase + (size_t)row * K + kb + (sb >> 1), (char*)dst + s * 8192 + w * 1024);
    }
  };

  // prologue: tile 0 fully into buf0 (8 loads/thread)
  stg(Abase, 0, As0, 0); stg(Abase, 0, As0, 1);
  stg(Bbase, 0, Bs0, 0); stg(Bbase, 0, Bs0, 1);
  __builtin_amdgcn_sched_barrier(0);

  for (int t = 0; t < nkt; ++t) {
    unsigned short* Asb = (t & 1) ? As1 : As0;
    unsigned short* Bsb = (t & 1) ? Bs1 : Bs0;
    unsigned short* Asn = (t & 1) ? As0 : As1;
    unsigned short* Bsn = (t & 1) ? Bs0 : Bs1;
    const int kbn = (t + 1 < nkt) ? (t + 1) << 6 : 0;  // dummy wrap keeps vmcnt invariant

    stg(Abase, kbn, Asn, 0);
    stg(Abase, kbn, Asn, 1);
    asm volatile("s_waitcnt vmcnt(4)" ::: "memory");
    __builtin_amdgcn_sched_barrier(0);
    __builtin_amdgcn_s_barrier();
    __builtin_amdgcn_sched_barrier(0);

    // B fragments for the whole tile (8 ds_read_b128), reused by all 4 phases
    bf16x8 bfr[4][2];
#pragma unroll
    for (int n = 0; n < 4; ++n) {
      const int row = wn * 64 + n * 16 + l15;
#pragma unroll
      for (int k = 0; k < 2; ++k) {
        const int off = (k * 64 + lg * 16) ^ ((row & 7) << 4);
        bfr[n][k] = *(const bf16x8*)((const char*)Bsb + row * 128 + off);
      }
    }
#pragma unroll
    for (int q = 0; q < 4; ++q) {
      bf16x8 af[2][2];
#pragma unroll
      for (int mm = 0; mm < 2; ++mm) {
        const int row = wm * 128 + (q * 2 + mm) * 16 + l15;
#pragma unroll
        for (int k = 0; k < 2; ++k) {
          const int off = (k * 64 + lg * 16) ^ ((row & 7) << 4);
          af[mm][k] = *(const bf16x8*)((const char*)Asb + row * 128 + off);
        }
      }
      if (q == 0) stg(Bbase, kbn, Bsn, 0);
      if (q == 1) stg(Bbase, kbn, Bsn, 1);
      __builtin_amdgcn_s_barrier();
      asm volatile("s_waitcnt lgkmcnt(0)" ::: "memory");
      __builtin_amdgcn_sched_barrier(0);
      __builtin_amdgcn_s_setprio(1);
#pragma unroll
      for (int mm = 0; mm < 2; ++mm)
#pragma unroll
        for (int n = 0; n < 4; ++n)
#pragma unroll
          for (int k = 0; k < 2; ++k)
            acc[q * 2 + mm][n] = __builtin_amdgcn_mfma_f32_16x16x32_bf16(
                af[mm][k], bfr[n][k], acc[q * 2 + mm][n], 0, 0, 0);
      __builtin_amdgcn_s_setprio(0);
      __builtin_amdgcn_sched_barrier(0);
      __builtin_amdgcn_s_barrier();
    }
  }

  if constexpr (EPI == EPI_EXP) {
    unsigned short* P = (unsigned short*)outv;
#pragma unroll
    for (int m = 0; m < 8; ++m) {
#pragma unroll
      for (int r = 0; r < 4; ++r) {
        const int row = mb + wm * 128 + m * 16 + lg * 4 + r;
        float ps = 0.f;
#pragma unroll
        for (int n = 0; n < 4; ++n) {
          const int col = nb + wn * 64 + n * 16 + l15;
          const float p = __expf(acc[m][n][r]);
          ps += p;
          P[((size_t)h * Sc + row) * Sc + col] = f2bf(p);
        }
#pragma unroll
        for (int d = 1; d < 16; d <<= 1) ps += __shfl_xor(ps, d);
        if (l15 == 0) atomicAdd(&extra[h * Sc + row], ps);
      }
    }
  } else {  // EPI_RELU (FFN1): out bf16 [row][2048]
#pragma unroll
    for (int m = 0; m < 8; ++m)
#pragma unroll
      for (int n = 0; n < 4; ++n) {
        const int col = nb + wn * 64 + n * 16 + l15;
        const float bv = bias[col];
#pragma unroll
        for (int r = 0; r < 4; ++r) {
          const int row = mb + wm * 128 + m * 16 + lg * 4 + r;
          ((unsigned short*)outv)[(size_t)row * 2048 + col] = f2bf(fmaxf(acc[m][n][r] + bv, 0.f));
        }
      }
  }
}

extern "C" void kernel_launch(void* const* d_in, const int* in_sizes, int n_in,
                              void* d_out, int out_size, void* d_ws, size_t ws_size,
                              hipStream_t stream)
{
  const float* fencs = (const float*)d_in[0];
  const float* Wq  = (const float*)d_in[1];
  const float* bq  = (const float*)d_in[2];
  const float* Wk  = (const float*)d_in[3];
  const float* bk  = (const float*)d_in[4];   // eliminated algebraically (softmax shift-invariance)
  const float* Wv  = (const float*)d_in[5];
  const float* bvv = (const float*)d_in[6];
  const float* W1  = (const float*)d_in[7];
  const float* b1  = (const float*)d_in[8];
  const float* W2  = (const float*)d_in[9];
  const float* b2  = (const float*)d_in[10];
  float* out = (float*)d_out;
  (void)bk;

  // ws layout, ushort elements; total 134,291,456 B <= proven 144,703,488
  if (ws_size < 134291456u) return;
  unsigned short* MTb = (unsigned short*)d_ws;            // [4][512][512]  (s*M^T)
  unsigned short* WvT = MTb + (size_t)1048576;            // [4][512][512]
  unsigned short* W1T = WvT + (size_t)1048576;            // [2048][512]; earlier: Wqs bf16
  unsigned short* W2T = W1T + (size_t)1048576;            // [512][2048]; earlier: Wkb bf16
  unsigned short* Xbf = W2T + (size_t)1048576;            // [4*2048][512]
  unsigned short* Qp  = Xbf + (size_t)4194304;            // [2,4,2048,512] pair; later attb
  unsigned short* VTp = Qp  + (size_t)8388608;            // [2,4,512,2048] pair
  unsigned short* P2  = VTp + (size_t)8388608;            // [8][2048][2048]; later hid
  float* attf = (float*)(P2 + (size_t)33554432);          // [4,2048,512] f32
  float* lbuf = attf + (size_t)4194304;                   // [8,2048] f32 per pair
  float* cvec = lbuf + (size_t)16384;                     // [4,512] f32
  unsigned short* Wqs  = W1T;                             // transient (dead before W1T built)
  unsigned short* Wkb  = W2T;
  unsigned short* attb = Qp;                              // overlay after pass1(p1)
  unsigned short* hid  = P2;                              // overlay after pass2(p1)

  // input + weight preprocessing
  k_cvt<<<4096, 256, 0, stream>>>(fencs, Xbf, 1048576, 1.0f);
  k_cvt<<<1024, 256, 0, stream>>>(Wq, Wqs, 262144, SCALE);
  k_cvt<<<1024, 256, 0, stream>>>(Wk, Wkb, 262144, 1.0f);
  k_vecmat<<<8, 256, 0, stream>>>(bq, Wk, cvec);
  // MT[h] = Wk_h @ (s*Wq_h)^T   (64 blocks, 0.5 GF)
  k_gemm<EPI_MT><<<dim3(4, 4, 4), 256, 0, stream>>>(
      Wkb, 262144, Wqs, 262144, 0, nullptr, MTb, nullptr, 512);
  k_wt<<<dim3(16, 16, 4), 256, 0, stream>>>(Wv, WvT, 512, 512, 1.0f);
  k_zero<<<4096, 256, 0, stream>>>(attf, 1048576);

  for (int p = 0; p < 2; ++p) {
    const unsigned short* Xp = Xbf + (size_t)p * 2097152;   // pair's 2 batches
    // Q' = X@(s*M) + c  (per pair, 4 heads, M=4096): 512 blocks
    k_gemm<EPI_QK><<<dim3(32, 4, 4), 256, 0, stream>>>(
        Xp, 0, MTb, 262144, 0, cvec, Qp, nullptr, 512);
    // V^T (per pair): 512 blocks
    k_gemm<EPI_V><<<dim3(32, 4, 4), 256, 0, stream>>>(
        Xp, 0, WvT, 262144, 0, bvv, VTp, nullptr, 512);
    k_zero<<<16, 256, 0, stream>>>(lbuf, 4096);
    // pass1 pair: P = exp(Q'@X^T), l = rowsum  (8-phase 256^2 core, 512 blocks)
    k_g8<EPI_EXP><<<dim3(8, 8, 8), 512, 0, stream>>>(
        Qp, 1048576, Xp, 1048576, 2, nullptr, P2, lbuf, 512);
    // pass2 pair: attf += (P@V^T) * 0.25/l  (512 blocks, K=2048)
    k_gemm<EPI_PV><<<dim3(16, 4, 8), 256, 0, stream>>>(
        P2, 4194304, VTp, 1048576, 0, nullptr,
        attf + (size_t)p * 2097152, lbuf, 2048);
  }

  // FFN weights (QKV bf16 scratch now dead)
  k_wt<<<dim3(16, 64, 1), 256, 0, stream>>>(W1, W1T, 512, 2048, 1.0f);
  k_wt<<<dim3(64, 16, 1), 256, 0, stream>>>(W2, W2T, 2048, 512, 1.0f);

  k_fin<<<4096, 256, 0, stream>>>(attf, attb, 1048576);

  // FFN1 on the 8-phase core (M=8192, N=2048: 256 blocks)
  k_g8<EPI_RELU><<<dim3(32, 8, 1), 512, 0, stream>>>(
      attb, 0, W1T, 0, 0, b1, hid, nullptr, 512);
  k_gemm<EPI_OUT><<<dim3(64, 4, 1), 256, 0, stream>>>(
      hid, 0, W2T, 0, 0, b2, out, attf, 2048);
}